// Round 1
// baseline (195.233 us; speedup 1.0000x reference)
//
#include <hip/hip_runtime.h>
#include <hip/hip_bf16.h>

#define NE 32
#define MM 256        // tokens per expert
#define DM 1024       // dmodel
#define ES 2048       // expert size

typedef __attribute__((ext_vector_type(8))) short short8;
typedef __attribute__((ext_vector_type(4))) float f32x4;
typedef unsigned int uint32;
typedef unsigned long long u64;
typedef unsigned short u16;

__device__ __forceinline__ u16 f2bf(float f) {
    uint32 u = __float_as_uint(f);
    u += 0x7fffu + ((u >> 16) & 1u);   // RNE (inputs are finite)
    return (u16)(u >> 16);
}

__device__ __forceinline__ u64 pack4(float a, float b, float c, float d) {
    return (u64)f2bf(a) | ((u64)f2bf(b) << 16) | ((u64)f2bf(c) << 32) | ((u64)f2bf(d) << 48);
}

// Swizzled byte offsets into LDS tiles. Both tiles are [row][64 elems] with a
// 128B row; the 16B slot index is XOR-swizzled by row bits so that fragment
// ds_read_b128 (16 lanes reading 16 different rows at the same k-slot) spreads
// across all eight 16B slots (<=2-way, free per m136). Writes use the SAME
// mapping (pure permutation of LDS => correct by construction).
__device__ __forceinline__ int a_off(int m, int k) {
    return m * 128 + ((((k >> 3) ^ (m & 7)) & 7) << 4) + (((k >> 2) & 1) << 3);
}
__device__ __forceinline__ int b_off(int n, int k) {
    int X = ((n >> 2) & 7) ^ ((n & 3) << 1);
    return n * 128 + ((((k >> 3) ^ X) & 7) << 4) + (((k >> 2) & 1) << 3);
}

// Grouped GEMM: C[e] = act(A[e] @ B[e]) over NE experts.
// A: [NE*MM][K] (row-major, K contiguous), elem = float or bf16(u16)
// B: [NE][K][N] (row-major, N contiguous), fp32 -> converted to bf16 in staging
// C: [NE*MM][N], elem = float or bf16(u16)
template<int N, int K, bool RELU, typename AT, typename CT>
__global__ __launch_bounds__(256) void ec_gemm(
    const AT* __restrict__ A,
    const float* __restrict__ B,
    CT* __restrict__ C)
{
    constexpr int BM = 128, BN = 128, BK = 64;
    constexpr int MT = MM / BM;   // 2
    constexpr int NT = N / BN;

    int bid = blockIdx.x;
    int e   = bid / (MT * NT);
    int rem = bid % (MT * NT);
    int mt  = rem / NT;
    int nt  = rem % NT;

    const AT*    Ae = A + (size_t)(e * MM + mt * BM) * K;
    const float* Be = B + (size_t)e * K * N + (size_t)nt * BN;
    CT*          Ce = C + (size_t)(e * MM + mt * BM) * N + (size_t)nt * BN;

    __shared__ short As[BM * BK];   // 16 KiB, bf16, swizzled [m][k]
    __shared__ short Bs[BN * BK];   // 16 KiB, bf16, swizzled transposed [n][k]
    char* AsB = (char*)As;
    char* BsB = (char*)Bs;

    const int t    = threadIdx.x;
    const int lane = t & 63;
    const int w    = t >> 6;          // wave 0..3
    const int wm   = (w >> 1) * 64;   // wave tile: 64x64
    const int wn   = (w & 1) * 64;
    const int lr   = lane & 15;
    const int lg   = lane >> 4;

    // staging assignments
    const int ak4 = (t & 15) * 4;     // A: k quad within BK
    const int am0 = t >> 4;           // A: base row (0..15), rows m0+16i
    const int bn4 = (t & 31) * 4;     // B: n quad within BN
    const int bkb = (t >> 5) * 4;     // B: k quad base (0..28), plus +32 group

    f32x4 acc[4][4] = {};

    for (int kt = 0; kt < K; kt += BK) {
        // ---------- stage A (convert f32->bf16 if needed) ----------
        if constexpr (sizeof(AT) == 4) {
            #pragma unroll
            for (int i = 0; i < 8; ++i) {
                int m = am0 + i * 16;
                float4 v = *(const float4*)((const float*)Ae + (size_t)m * K + kt + ak4);
                *(u64*)(AsB + a_off(m, ak4)) = pack4(v.x, v.y, v.z, v.w);
            }
        } else {
            #pragma unroll
            for (int i = 0; i < 8; ++i) {
                int m = am0 + i * 16;
                u64 v = *(const u64*)((const u16*)Ae + (size_t)m * K + kt + ak4);
                *(u64*)(AsB + a_off(m, ak4)) = v;
            }
        }
        // ---------- stage B: 4x4 register transpose + convert ----------
        #pragma unroll
        for (int g = 0; g < 2; ++g) {
            int k4 = g * 32 + bkb;
            const float* Bk = Be + (size_t)(kt + k4) * N + bn4;
            float4 r0 = *(const float4*)(Bk);
            float4 r1 = *(const float4*)(Bk + N);
            float4 r2 = *(const float4*)(Bk + 2 * (size_t)N);
            float4 r3 = *(const float4*)(Bk + 3 * (size_t)N);
            *(u64*)(BsB + b_off(bn4 + 0, k4)) = pack4(r0.x, r1.x, r2.x, r3.x);
            *(u64*)(BsB + b_off(bn4 + 1, k4)) = pack4(r0.y, r1.y, r2.y, r3.y);
            *(u64*)(BsB + b_off(bn4 + 2, k4)) = pack4(r0.z, r1.z, r2.z, r3.z);
            *(u64*)(BsB + b_off(bn4 + 3, k4)) = pack4(r0.w, r1.w, r2.w, r3.w);
        }
        __syncthreads();
        // ---------- compute ----------
        #pragma unroll
        for (int kk = 0; kk < 2; ++kk) {
            int k = kk * 32 + lg * 8;   // 8-aligned -> 16B-aligned slot
            short8 af[4], bfr[4];
            #pragma unroll
            for (int i = 0; i < 4; ++i)
                af[i] = *(const short8*)(AsB + a_off(wm + i * 16 + lr, k));
            #pragma unroll
            for (int j = 0; j < 4; ++j)
                bfr[j] = *(const short8*)(BsB + b_off(wn + j * 16 + lr, k));
            #pragma unroll
            for (int i = 0; i < 4; ++i)
                #pragma unroll
                for (int j = 0; j < 4; ++j)
                    acc[i][j] = __builtin_amdgcn_mfma_f32_16x16x32_bf16(af[i], bfr[j], acc[i][j], 0, 0, 0);
        }
        __syncthreads();
    }

    // ---------- epilogue: C/D layout col=lane&15, row=(lane>>4)*4+reg ----------
    #pragma unroll
    for (int i = 0; i < 4; ++i) {
        #pragma unroll
        for (int rr = 0; rr < 4; ++rr) {
            int row = wm + i * 16 + lg * 4 + rr;
            CT* Cp = Ce + (size_t)row * N + wn + lr;
            #pragma unroll
            for (int j = 0; j < 4; ++j) {
                float v = acc[i][j][rr];
                if constexpr (RELU) v = v > 0.0f ? v : 0.0f;
                if constexpr (sizeof(CT) == 2) {
                    ((u16*)Cp)[j * 16] = f2bf(v);
                } else {
                    ((float*)Cp)[j * 16] = v;
                }
            }
        }
    }
}

extern "C" void kernel_launch(void* const* d_in, const int* in_sizes, int n_in,
                              void* d_out, int out_size, void* d_ws, size_t ws_size,
                              hipStream_t stream) {
    const float* x    = (const float*)d_in[0];
    // d_in[1] = gate: dead code in the reference output -- unused.
    const float* lin1 = (const float*)d_in[2];
    const float* lin2 = (const float*)d_in[3];
    float* out = (float*)d_out;
    u16* h = (u16*)d_ws;   // [NE][MM][ES] bf16 = 33.5 MB (relu already applied)

    dim3 blk(256);
    // GEMM1: h = relu(x @ W1), per expert 256x2048, K=1024
    ec_gemm<ES, DM, true,  float, u16 ><<<NE * (MM/128) * (ES/128), blk, 0, stream>>>(x, lin1, h);
    // GEMM2: out = h @ W2, per expert 256x1024, K=2048
    ec_gemm<DM, ES, false, u16,  float><<<NE * (MM/128) * (DM/128), blk, 0, stream>>>(h, lin2, out);
}